// Round 4
// baseline (568.308 us; speedup 1.0000x reference)
//
#include <hip/hip_runtime.h>
#include <stdint.h>

#define B_ 8
#define T_ 256
#define S_ 512
#define D_ 768
#define H_ 8
#define V_ 32000
#define BLOCK 1024
#define NWAVE (BLOCK / 64)       // 16
#define NF4 (V_ / 4)             // 8000 float4 per row
#define TAIL (NF4 - 7 * BLOCK)   // 832: tid < TAIL has an 8th chunk
#define ROWS 8
#define GRID (B_ * T_ / ROWS)    // 256 blocks = 1 per CU (residency-forced spread)
#define SLOTS 1024               // hash slots (max 512 keys)
#define EMPTYK 0xFFFFFFFFu
#define BMW ((V_ + 31) / 32)     // 1000 bitmap words

typedef float vf4 __attribute__((ext_vector_type(4)));

struct LBuf {
    unsigned int hkey[SLOTS];   // 4 KB
    float        hval[SLOTS];   // 4 KB
    unsigned int bmap[BMW];     // 4000 B
};

static __device__ __forceinline__ vf4 expv(vf4 v) {
    vf4 r;
    r.x = __expf(v.x);
    r.y = __expf(v.y);
    r.z = __expf(v.z);
    r.w = __expf(v.w);
    return r;
}

__global__ __launch_bounds__(BLOCK, 4) void ptrgen_f32(
    const float* __restrict__ dec,   // (B,T,D)
    const float* __restrict__ fin,   // (B,T,V)
    const float* __restrict__ attw,  // (B,H,T,S)
    const int* __restrict__ enc,     // (B,S)
    const float* __restrict__ W,     // (D,1)
    const float* __restrict__ bbias, // (1,)
    float* __restrict__ out)         // (B,T,V)
{
    __shared__ LBuf lb[3];           // triple-buffered scatter state, ~36.6 KB
    __shared__ float sred[3 * NWAVE];
    __shared__ float sbc[3];

    const int tid = threadIdx.x;
    const int base = blockIdx.x * ROWS;   // 8 consecutive rows, same b (8 | 256)
    const int b = base >> 8;
    const int lane = tid & 63, wid = tid >> 6;
    const bool isS = tid < S_;
    const bool isD = tid < D_;
    const bool hasT = tid < TAIL;

    // per-block constants (enc row is the same for all 8 rows)
    const float Wv = isD ? W[tid] : 0.0f;
    const int token = isS ? enc[b * S_ + tid] : 0;
    const float bb = bbias[0];
    const unsigned int hash0 = ((unsigned int)token * 2654435761u) >> 22;

    // ---- prologue: smalls for row 0 (one-time stall is fine) ----
    float pp_c = 0.0f, ae_c = 0.0f;
    if (isD) pp_c = dec[(size_t)base * D_ + tid] * Wv;
    if (isS) {
        const float* ab = attw + ((size_t)(b * H_) * T_ + (base & 255)) * S_ + tid;
        float s = 0.0f;
#pragma unroll
        for (int h = 0; h < H_; ++h) s += ab[(size_t)h * (T_ * S_)];
        ae_c = __expf(s * (1.0f / H_));
    }
    // zero lb[0], then scatter row 0
    for (int k = tid; k < SLOTS; k += BLOCK) { lb[0].hkey[k] = EMPTYK; lb[0].hval[k] = 0.0f; }
    for (int k = tid; k < BMW; k += BLOCK) lb[0].bmap[k] = 0u;
    __syncthreads();
    if (isS) {
        atomicOr(&lb[0].bmap[token >> 5], 1u << (token & 31));
        unsigned int h = hash0;
        for (;;) {
            unsigned int prev = atomicCAS(&lb[0].hkey[h], EMPTYK, (unsigned int)token);
            if (prev == EMPTYK || prev == (unsigned int)token) { atomicAdd(&lb[0].hval[h], ae_c); break; }
            h = (h + 1) & (SLOTS - 1);
        }
    }

    // register double-buffer for row data (exp values, 32+32 VGPR)
    vf4 Areg[8], Breg[8];
    {
        const vf4* rowf = (const vf4*)(fin + (size_t)base * V_);
#pragma unroll
        for (int j = 0; j < 7; ++j) Areg[j] = __builtin_nontemporal_load(rowf + tid + j * BLOCK);
        Areg[7] = hasT ? __builtin_nontemporal_load(rowf + tid + 7 * BLOCK) : (vf4)(0.0f);
    }

    float pp_n = 0.0f, ae_n = 0.0f;

    auto body = [&](int i, vf4* CUR, vf4* NXT) {
        const int row = base + i;
        const bool more = (i < ROWS - 1);

        // 1. issue next-row smalls EARLY (latency hides under exp+reduce)
        float aw[8] = {0, 0, 0, 0, 0, 0, 0, 0};
        float dv = 0.0f;
        if (more) {
            if (isS) {
                const float* ab = attw + ((size_t)(b * H_) * T_ + ((row + 1) & 255)) * S_ + tid;
#pragma unroll
                for (int h = 0; h < H_; ++h) aw[h] = ab[(size_t)h * (T_ * S_)];
            }
            if (isD) dv = dec[(size_t)(row + 1) * D_ + tid];
        }

        // 2. exp in place (single exp per element, stays in registers)
        float lsum = 0.0f;
#pragma unroll
        for (int j = 0; j < 7; ++j) {
            CUR[j] = expv(CUR[j]);
            lsum += CUR[j].x + CUR[j].y + CUR[j].z + CUR[j].w;
        }
        if (hasT) {
            CUR[7] = expv(CUR[7]);
            lsum += CUR[7].x + CUR[7].y + CUR[7].z + CUR[7].w;
        } else {
            CUR[7] = (vf4)(0.0f);
        }

        // 3. zero the scatter target for row i+1 (rides on the reduction barriers;
        //    its previous reader emit(i-2) is separated by barrier1(i-1))
        LBuf* zb = &lb[(i + 1) % 3];
        for (int k = tid; k < SLOTS; k += BLOCK) { zb->hkey[k] = EMPTYK; zb->hval[k] = 0.0f; }
        for (int k = tid; k < BMW; k += BLOCK) zb->bmap[k] = 0u;

        // 4/5. triple block reduction (pp, ae, lsum); only cheap drains at barriers
        float v0 = pp_c, v1 = ae_c, v2 = lsum;
#pragma unroll
        for (int o = 32; o; o >>= 1) {
            v0 += __shfl_xor(v0, o, 64);
            v1 += __shfl_xor(v1, o, 64);
            v2 += __shfl_xor(v2, o, 64);
        }
        if (lane == 0) { sred[wid] = v0; sred[NWAVE + wid] = v1; sred[2 * NWAVE + wid] = v2; }
        __syncthreads();
        if (wid == 0) {
            float a0 = (lane < NWAVE) ? sred[lane] : 0.0f;
            float a1 = (lane < NWAVE) ? sred[NWAVE + lane] : 0.0f;
            float a2 = (lane < NWAVE) ? sred[2 * NWAVE + lane] : 0.0f;
#pragma unroll
            for (int o = 8; o; o >>= 1) {
                a0 += __shfl_xor(a0, o, 64);
                a1 += __shfl_xor(a1, o, 64);
                a2 += __shfl_xor(a2, o, 64);
            }
            if (lane == 0) { sbc[0] = a0; sbc[1] = a1; sbc[2] = a2; }
        }
        __syncthreads();

        const float p_gen  = 1.0f / (1.0f + __expf(-(sbc[0] + bb)));
        const float inv_l  = p_gen / sbc[2];
        const float cscale = (1.0f - p_gen) / sbc[1];

        // 6. issue next-row big loads NOW (after barriers -> never drained by them;
        //    they fly during the whole emit phase), then scatter row i+1
        if (more) {
            const vf4* rowf = (const vf4*)(fin + (size_t)(row + 1) * V_);
#pragma unroll
            for (int j = 0; j < 7; ++j) NXT[j] = __builtin_nontemporal_load(rowf + tid + j * BLOCK);
            NXT[7] = hasT ? __builtin_nontemporal_load(rowf + tid + 7 * BLOCK) : (vf4)(0.0f);
            pp_n = isD ? dv * Wv : 0.0f;
            if (isS) {
                float s = aw[0] + aw[1] + aw[2] + aw[3] + aw[4] + aw[5] + aw[6] + aw[7];
                ae_n = __expf(s * (1.0f / H_));
                atomicOr(&zb->bmap[token >> 5], 1u << (token & 31));
                unsigned int h = hash0;
                for (;;) {
                    unsigned int prev = atomicCAS(&zb->hkey[h], EMPTYK, (unsigned int)token);
                    if (prev == EMPTYK || prev == (unsigned int)token) { atomicAdd(&zb->hval[h], ae_n); break; }
                    h = (h + 1) & (SLOTS - 1);
                }
            } else {
                ae_n = 0.0f;
            }
        }

        // 7. emit row i from registers + lb[i%3] (loads for i+1 in flight under this)
        LBuf* eb = &lb[i % 3];
        vf4* outp = (vf4*)(out + (size_t)row * V_);
        auto hget = [&](int idx) -> float {
            unsigned int h = ((unsigned int)idx * 2654435761u) >> 22;
            for (;;) {
                unsigned int k = eb->hkey[h];
                if (k == (unsigned int)idx) return eb->hval[h];
                if (k == EMPTYK) return 0.0f;
                h = (h + 1) & (SLOTS - 1);
            }
        };
#pragma unroll
        for (int j = 0; j < 8; ++j) {
            if (j < 7 || hasT) {
                const int c = tid + j * BLOCK;
                const vf4 e = CUR[j];
                const unsigned int nib = (eb->bmap[c >> 3] >> ((c & 7) * 4)) & 0xFu;
                float c0 = 0.0f, c1 = 0.0f, c2 = 0.0f, c3 = 0.0f;
                if (nib) {
                    if (nib & 1u) c0 = hget(4 * c + 0);
                    if (nib & 2u) c1 = hget(4 * c + 1);
                    if (nib & 4u) c2 = hget(4 * c + 2);
                    if (nib & 8u) c3 = hget(4 * c + 3);
                }
                vf4 y;
                y.x = __logf(fmaf(e.x, inv_l, fmaf(c0, cscale, 0.001f)));
                y.y = __logf(fmaf(e.y, inv_l, fmaf(c1, cscale, 0.001f)));
                y.z = __logf(fmaf(e.z, inv_l, fmaf(c2, cscale, 0.001f)));
                y.w = __logf(fmaf(e.w, inv_l, fmaf(c3, cscale, 0.001f)));
                __builtin_nontemporal_store(y, outp + c);
            }
        }
        pp_c = pp_n;
        ae_c = ae_n;
    };

    // explicit A/B alternation keeps every register index compile-time static
#pragma unroll
    for (int ii = 0; ii < ROWS; ii += 2) {
        body(ii, Areg, Breg);
        body(ii + 1, Breg, Areg);
    }
}

extern "C" void kernel_launch(void* const* d_in, const int* in_sizes, int n_in,
                              void* d_out, int out_size, void* d_ws, size_t ws_size,
                              hipStream_t stream) {
    const float* dec   = (const float*)d_in[0];
    const float* fin   = (const float*)d_in[1];
    const float* attw  = (const float*)d_in[2];
    const int*   enc   = (const int*)d_in[3];
    const float* W     = (const float*)d_in[4];
    const float* bbias = (const float*)d_in[5];
    float* out = (float*)d_out;

    ptrgen_f32<<<GRID, BLOCK, 0, stream>>>(dec, fin, attw, enc, W, bbias, out);
}